// Round 5
// baseline (212.536 us; speedup 1.0000x reference)
//
#include <hip/hip_runtime.h>
#include <hip/hip_bf16.h>

#define NROWS 131072
#define DK    1024
#define CCLS  21
#define CTF   84
#define NCOL  105          // 21 + 84
#define NCT   7            // 112 padded cols / 16
#define WROWS 16           // rows per wave (one MFMA row-tile)
#define SLABF 256          // f32 per row per slab = 1KB burst per row
#define NSLAB (DK / SLABF) // 4
#define KTPS  (SLABF / 32) // 8 k-tiles per slab

typedef __attribute__((ext_vector_type(4))) float f32x4;
typedef __attribute__((ext_vector_type(8))) short bf16x8;

typedef const __attribute__((address_space(1))) void GV;
typedef __attribute__((address_space(3))) void LV;

__device__ __forceinline__ unsigned short f2bf_rne(float x) {
    union { float f; unsigned u; } v; v.f = x;
    unsigned r = v.u + 0x7fffu + ((v.u >> 16) & 1u);
    return (unsigned short)(r >> 16);
}

__device__ __forceinline__ unsigned pack2(float lo, float hi) {
    union { float f; unsigned u; } a, b; a.f = lo; b.f = hi;
    return ((a.u + 0x8000u) >> 16) | ((b.u + 0x8000u) & 0xffff0000u);
}

__device__ __forceinline__ bf16x8 cvt8v(const f32x4 lo, const f32x4 hi) {
    union { unsigned u[4]; bf16x8 v; } r;
    r.u[0] = pack2(lo[0], lo[1]);
    r.u[1] = pack2(lo[2], lo[3]);
    r.u[2] = pack2(hi[0], hi[1]);
    r.u[3] = pack2(hi[2], hi[3]);
    return r.v;
}

// Pack [W_cls | W_tf | zero-pad] into bf16 MFMA B-fragment order (verified):
// element ((kt*NCT+ct)*64+lane)*8 + j = B[k][col],
// col = ct*16 + (lane&15), k = kt*32 + (lane>>4)*8 + j
__global__ void pack_B_kernel(const float* __restrict__ Wc,
                              const float* __restrict__ Wt,
                              unsigned short* __restrict__ Bp) {
    const int frag = blockIdx.x;           // 224 total
    const int kt = frag / NCT, ct = frag % NCT;
    const int lane = threadIdx.x;          // 64
    const int col = ct * 16 + (lane & 15);
    const int k0  = kt * 32 + ((lane >> 4) << 3);
    bf16x8 o;
#pragma unroll
    for (int j = 0; j < 8; ++j) {
        const int k = k0 + j;
        float v = 0.0f;
        if (col < CCLS)      v = Wc[k * CCLS + col];
        else if (col < NCOL) v = Wt[k * CTF + (col - CCLS)];
        o[j] = (short)f2bf_rne(v);
    }
    *reinterpret_cast<bf16x8*>(Bp + ((size_t)frag * 64 + lane) * 8) = o;
}

// Max-burst DMA GEMM: wave-private 16 rows, slab = 16 rows x 1KB contiguous
// per row (one DMA inst per full row-slab), double-buffered, forced wait on
// DMA only (vmcnt(16)); B-fragment loads float inside compute with
// compiler-counted waits. No __syncthreads anywhere.
__global__ __launch_bounds__(128)
void roi_gemm_kernel(const float* __restrict__ F,
                     const unsigned short* __restrict__ Bp,
                     const float* __restrict__ bcls,
                     const float* __restrict__ btf,
                     float* __restrict__ out) {
    // [wave][buf][row][f32] = 2*2*16*256*4 = 64 KiB
    __shared__ float Alds[2][2][WROWS][SLABF];

    const int t    = threadIdx.x;
    const int wave = t >> 6;         // 0..1
    const int lane = t & 63;
    const int fr   = lane & 15;      // A/C row-in-tile, B col
    const int fq   = lane >> 4;      // 0..3
    const int sw   = fr & 7;         // read-side XOR swizzle (16B-chunk units)

    const long rww = (long)blockIdx.x * (2 * WROWS) + wave * WROWS;

    // DMA inst q (q=0..15) fills row q linearly (64 lanes x 16B = 1KB).
    // LDS slot s=lane must hold global chunk s ^ (q&7)  (read-side XOR undoes
    // it; row stride 1KB = bank-aligned, so rows must be rotated).
    // p[j] = source for rows j and j+8 (same XOR pattern since (q&7) matches).
    const float* p[8];
#pragma unroll
    for (int j = 0; j < 8; ++j)
        p[j] = F + (size_t)(rww + j) * DK + ((lane ^ j) << 2);

    const unsigned short* bb = Bp + (size_t)lane * 8;

    f32x4 acc[NCT];
#pragma unroll
    for (int b = 0; b < NCT; ++b) acc[b] = (f32x4){0.f, 0.f, 0.f, 0.f};

#define STAGE(BUF, S) do {                                                    \
    _Pragma("unroll")                                                         \
    for (int q = 0; q < 16; ++q) {                                            \
        const float* g = p[q & 7] + ((q >> 3) ? (size_t)8 * DK : (size_t)0)   \
                         + (size_t)(S) * SLABF;                               \
        __builtin_amdgcn_global_load_lds((GV*)g,                              \
            (LV*)&Alds[wave][BUF][q][0], 16, 0, 0);                           \
    }                                                                         \
} while (0)

    STAGE(0, 0);   // prologue: 16 DMA outstanding

    for (int s = 0; s < NSLAB; ++s) {
        const int buf = s & 1;

        __builtin_amdgcn_sched_barrier(0);
        if (s + 1 < NSLAB) {
            STAGE(buf ^ 1, s + 1);
            __builtin_amdgcn_sched_barrier(0);
            // FIFO: [DMA(s)=16][DMA(s+1)=16] -> completes DMA(s), keeps
            // DMA(s+1) in flight under this slab's compute.
            asm volatile("s_waitcnt vmcnt(16)" ::: "memory");
        } else {
            asm volatile("s_waitcnt vmcnt(0)" ::: "memory");
        }
        __builtin_amdgcn_sched_barrier(0);

        const float* lpr = &Alds[wave][buf][fr][0];
#pragma unroll
        for (int kt = 0; kt < KTPS; ++kt) {
            const int gkt = s * KTPS + kt;
            bf16x8 bf[NCT];
#pragma unroll
            for (int ct = 0; ct < NCT; ++ct)
                bf[ct] = *reinterpret_cast<const bf16x8*>(
                    bb + ((size_t)(gkt * NCT + ct) * 512));
            const int c0 = kt * 8 + fq * 2;
            const f32x4 lo = *reinterpret_cast<const f32x4*>(
                lpr + (((c0 + 0) ^ sw) << 2));
            const f32x4 hi = *reinterpret_cast<const f32x4*>(
                lpr + (((c0 + 1) ^ sw) << 2));
            const bf16x8 af = cvt8v(lo, hi);
#pragma unroll
            for (int ct = 0; ct < NCT; ++ct)
                acc[ct] = __builtin_amdgcn_mfma_f32_16x16x32_bf16(
                    af, bf[ct], acc[ct], 0, 0, 0);
        }
    }
#undef STAGE

    // epilogue: bias + scatter into the two outputs (layout verified)
    float* out_tf = out + (size_t)NROWS * CCLS;
    const long rbase = rww + (fq << 2);
#pragma unroll
    for (int ct = 0; ct < NCT; ++ct) {
        const int col = ct * 16 + fr;
        if (col >= NCOL) continue;
        const float bias = (col < CCLS) ? bcls[col] : btf[col - CCLS];
#pragma unroll
        for (int j = 0; j < 4; ++j) {
            const long row = rbase + j;
            const float v = acc[ct][j] + bias;
            if (col < CCLS) out[row * CCLS + col] = v;
            else            out_tf[row * CTF + (col - CCLS)] = v;
        }
    }
}

extern "C" void kernel_launch(void* const* d_in, const int* in_sizes, int n_in,
                              void* d_out, int out_size, void* d_ws, size_t ws_size,
                              hipStream_t stream) {
    const float* F  = (const float*)d_in[0];
    const float* Wc = (const float*)d_in[1];
    const float* bc = (const float*)d_in[2];
    const float* Wt = (const float*)d_in[3];
    const float* bt = (const float*)d_in[4];
    unsigned short* Bp = (unsigned short*)d_ws;   // 229,376 B

    pack_B_kernel<<<NCT * (DK / 32), 64, 0, stream>>>(Wc, Wt, Bp);
    roi_gemm_kernel<<<NROWS / (2 * WROWS), 128, 0, stream>>>(F, Bp, bc, bt,
                                                             (float*)d_out);
}

// Round 6
// 159.821 us; speedup vs baseline: 1.3298x; 1.3298x over previous
//
#include <hip/hip_runtime.h>
#include <hip/hip_bf16.h>

#define NROWS 131072
#define DK    1024
#define CCLS  21
#define CTF   84
#define NCOL  105          // 21 + 84
#define NCT   7            // 112 padded cols / 16
#define BM    128          // 4 waves x 32 rows
#define SLABF 32           // f32 per row per slab (128 B burst, 1 k-tile)
#define NSLAB (DK / SLABF) // 32

typedef __attribute__((ext_vector_type(4))) float f32x4;
typedef __attribute__((ext_vector_type(8))) short bf16x8;

typedef const __attribute__((address_space(1))) void GV;
typedef __attribute__((address_space(3))) void LV;

__device__ __forceinline__ unsigned short f2bf_rne(float x) {
    union { float f; unsigned u; } v; v.f = x;
    unsigned r = v.u + 0x7fffu + ((v.u >> 16) & 1u);
    return (unsigned short)(r >> 16);
}

__device__ __forceinline__ unsigned pack2(float lo, float hi) {
    union { float f; unsigned u; } a, b; a.f = lo; b.f = hi;
    return ((a.u + 0x8000u) >> 16) | ((b.u + 0x8000u) & 0xffff0000u);
}

__device__ __forceinline__ bf16x8 cvt8v(const f32x4 lo, const f32x4 hi) {
    union { unsigned u[4]; bf16x8 v; } r;
    r.u[0] = pack2(lo[0], lo[1]);
    r.u[1] = pack2(lo[2], lo[3]);
    r.u[2] = pack2(hi[0], hi[1]);
    r.u[3] = pack2(hi[2], hi[3]);
    return r.v;
}

// Pack [W_cls | W_tf | zero-pad] into bf16 MFMA B-fragment order (verified):
// element ((kt*NCT+ct)*64+lane)*8 + j = B[k][col],
// col = ct*16 + (lane&15), k = kt*32 + (lane>>4)*8 + j
__global__ void pack_B_kernel(const float* __restrict__ Wc,
                              const float* __restrict__ Wt,
                              unsigned short* __restrict__ Bp) {
    const int frag = blockIdx.x;           // 224 total
    const int kt = frag / NCT, ct = frag % NCT;
    const int lane = threadIdx.x;          // 64
    const int col = ct * 16 + (lane & 15);
    const int k0  = kt * 32 + ((lane >> 4) << 3);
    bf16x8 o;
#pragma unroll
    for (int j = 0; j < 8; ++j) {
        const int k = k0 + j;
        float v = 0.0f;
        if (col < CCLS)      v = Wc[k * CCLS + col];
        else if (col < NCOL) v = Wt[k * CTF + (col - CCLS)];
        o[j] = (short)f2bf_rne(v);
    }
    *reinterpret_cast<bf16x8*>(Bp + ((size_t)frag * 64 + lane) * 8) = o;
}

// R4 structure at 2x occupancy: wave-private 32 rows, slab = 128B/row
// (1 k-tile), double-buffered DMA with counted vmcnt(4), 32KB LDS/block,
// VGPR capped for 4 blocks/CU = 16 waves/CU. No __syncthreads anywhere.
__global__ __launch_bounds__(256, 4)
void roi_gemm_kernel(const float* __restrict__ F,
                     const unsigned short* __restrict__ Bp,
                     const float* __restrict__ bcls,
                     const float* __restrict__ btf,
                     float* __restrict__ out) {
    // [buf][wave][row][f32] = 2*4*32*128B = 32 KiB
    __shared__ float Alds[2][4][32][SLABF];

    const int t    = threadIdx.x;
    const int wave = t >> 6;
    const int lane = t & 63;
    const int fr   = lane & 15;      // A/C row-in-tile, B col
    const int fq   = lane >> 4;      // 0..3
    const int sw   = fr & 7;         // read-side XOR swizzle (16B-slot units)

    const long rw = (long)blockIdx.x * BM + wave * 32;

    // DMA instr q (0..3) fills rows q*8..q*8+7 linearly (8 lanes/row, 16B).
    // Lane l: row q*8+(l>>3), slot l&7. Slot s must hold global chunk
    // s ^ (row&7) = (l&7) ^ (l>>3)  (same for all q since row&7 = l>>3).
    const float* psrc[4];
#pragma unroll
    for (int q = 0; q < 4; ++q)
        psrc[q] = F + (size_t)(rw + q * 8 + (lane >> 3)) * DK
                    + (((lane & 7) ^ (lane >> 3)) << 2);

    const unsigned short* bb = Bp + (size_t)lane * 8;

    f32x4 acc[2][NCT];
#pragma unroll
    for (int a = 0; a < 2; ++a)
#pragma unroll
        for (int b = 0; b < NCT; ++b)
            acc[a][b] = (f32x4){0.f, 0.f, 0.f, 0.f};

#define STAGE(BUF, S) do {                                                    \
    _Pragma("unroll")                                                         \
    for (int q = 0; q < 4; ++q)                                               \
        __builtin_amdgcn_global_load_lds((GV*)(psrc[q] + (size_t)(S) * SLABF),\
            (LV*)&Alds[BUF][wave][q * 8][0], 16, 0, 0);                       \
} while (0)

    STAGE(0, 0);   // prologue: 4 DMA outstanding

    for (int s = 0; s < NSLAB; ++s) {
        const int buf = s & 1;

        __builtin_amdgcn_sched_barrier(0);
        // B fragments for this k-tile (7 loads, L2-resident)
        bf16x8 bf[NCT];
#pragma unroll
        for (int ct = 0; ct < NCT; ++ct)
            bf[ct] = *reinterpret_cast<const bf16x8*>(
                bb + ((size_t)(s * NCT + ct) * 512));
        __builtin_amdgcn_sched_barrier(0);

        // FIFO: [D(s)=4][B(s)=7][D(s+1)=4] -> vmcnt(4) completes D(s)+B(s),
        // keeps D(s+1) in flight under this slab's compute.
        if (s + 1 < NSLAB) {
            STAGE(buf ^ 1, s + 1);
            __builtin_amdgcn_sched_barrier(0);
            asm volatile("s_waitcnt vmcnt(4)" ::: "memory");
        } else {
            asm volatile("s_waitcnt vmcnt(0)" ::: "memory");
        }
        __builtin_amdgcn_sched_barrier(0);

        bf16x8 af[2];
#pragma unroll
        for (int rt = 0; rt < 2; ++rt) {
            const float* lpr = &Alds[buf][wave][rt * 16 + fr][0];
            const f32x4 lo = *reinterpret_cast<const f32x4*>(
                lpr + (((fq * 2 + 0) ^ sw) << 2));
            const f32x4 hi = *reinterpret_cast<const f32x4*>(
                lpr + (((fq * 2 + 1) ^ sw) << 2));
            af[rt] = cvt8v(lo, hi);
        }
#pragma unroll
        for (int ct = 0; ct < NCT; ++ct) {
            acc[0][ct] = __builtin_amdgcn_mfma_f32_16x16x32_bf16(
                af[0], bf[ct], acc[0][ct], 0, 0, 0);
            acc[1][ct] = __builtin_amdgcn_mfma_f32_16x16x32_bf16(
                af[1], bf[ct], acc[1][ct], 0, 0, 0);
        }
    }
#undef STAGE

    // epilogue: bias + scatter into the two outputs (layout verified)
    float* out_tf = out + (size_t)NROWS * CCLS;
#pragma unroll
    for (int rt = 0; rt < 2; ++rt) {
        const long rbase = rw + rt * 16 + (fq << 2);
#pragma unroll
        for (int ct = 0; ct < NCT; ++ct) {
            const int col = ct * 16 + fr;
            if (col >= NCOL) continue;
            const float bias = (col < CCLS) ? bcls[col] : btf[col - CCLS];
#pragma unroll
            for (int j = 0; j < 4; ++j) {
                const long row = rbase + j;
                const float v = acc[rt][ct][j] + bias;
                if (col < CCLS) out[row * CCLS + col] = v;
                else            out_tf[row * CTF + (col - CCLS)] = v;
            }
        }
    }
}

extern "C" void kernel_launch(void* const* d_in, const int* in_sizes, int n_in,
                              void* d_out, int out_size, void* d_ws, size_t ws_size,
                              hipStream_t stream) {
    const float* F  = (const float*)d_in[0];
    const float* Wc = (const float*)d_in[1];
    const float* bc = (const float*)d_in[2];
    const float* Wt = (const float*)d_in[3];
    const float* bt = (const float*)d_in[4];
    unsigned short* Bp = (unsigned short*)d_ws;   // 229,376 B

    pack_B_kernel<<<NCT * (DK / 32), 64, 0, stream>>>(Wc, Wt, Bp);
    roi_gemm_kernel<<<NROWS / BM, 256, 0, stream>>>(F, Bp, bc, bt,
                                                    (float*)d_out);
}